// Round 10
// baseline (17.863 us; speedup 1.0000x reference)
//
#include <hip/hip_runtime.h>
#include <hip/hip_bf16.h>
#include <math.h>

// Shapes fixed by reference: B=2, L=385, C=128, N=384, 2C=256
// Verified identity (rounds 0-9 all passed):
//   out[b,1+i,c] = b[c] + sum_{kk=0}^{255} (coefA[b,kk]*F[b,i,kk&127] + coefB[b,kk]) * W[c,kk]
//     coefA[kk] = -s_kk (kk<128) | gamma[kk] (kk>=128)
//     coefB[kk] = s_kk*M_kk + beta[kk] (kk<128) | beta[kk] (kk>=128)
//     s_k = gamma[k]/sqrt(var_j F[:,k]+eps);  M_k = sum_j softmax_j(s_k F[j,k]) F[j,k]
// R9 structure (wave-private stats, 1 barrier) + B-operand direct from global:
// W fragments are loaded per-lane from L2-warm W (issued post-exp so the 64
// transient f32 regs don't overlap the 48-reg v[] live range; latency hides
// under butterfly2 + As build + barrier), converted to bf16 in regs. No Wb
// LDS array at all: MFMA reads only the A operand from LDS.

#define B_   2
#define L_   385
#define C_   128
#define N_   384
#define LC_  (L_ * C_)
#define EPS_ 1e-5f
#define RB_  12
#define NTHR_ 1024
#define LOG2E_ 1.44269504088896340736f

typedef short short8 __attribute__((ext_vector_type(8)));
typedef float f32x4 __attribute__((ext_vector_type(4)));

union V16 { ushort us[8]; uint4 v4; short8 s8; };
union V8u { ushort us[4]; uint2 u2; };

__device__ inline ushort f2bf(float f) {
  __hip_bfloat16 hb = __float2bfloat16(f);   // hw RNE
  return __builtin_bit_cast(ushort, hb);
}

__device__ inline float fast_exp2(float xv) {
#if __has_builtin(__builtin_amdgcn_exp2f)
  return __builtin_amdgcn_exp2f(xv);
#else
  float r;
  asm("v_exp_f32 %0, %1" : "=v"(r) : "v"(xv));
  return r;
#endif
}

__global__ __launch_bounds__(NTHR_, 1) void lnp_kernel(
    const float* __restrict__ x, const float* __restrict__ gamma,
    const float* __restrict__ beta, const float* __restrict__ W,
    const float* __restrict__ bvec, float* __restrict__ out) {
  __shared__ __align__(16) ushort As[32 * 256];   // [i][kk^((i&7)<<3)] bf16

  const int blk = blockIdx.x;
  const int b   = blk / RB_;
  const int rt  = blk % RB_;
  const int r0  = rt * 32;
  const int t   = threadIdx.x;
  const int w   = t >> 6;
  const int l   = t & 63;
  const int half = l & 1;
  const int rr  = l >> 1;            // row-within-tile this lane owns
  const int ch4 = 8 * w + half * 4;  // 4 owned channels

  const float* Fb = x + (size_t)b * LC_ + C_;   // F[j][c] = Fb[j*128+c]

  // MFMA tile indices
  const int l16 = l & 15, lg = l >> 4, tn = w & 7, tm = w >> 3;
  const int bc = tn * 16 + l16;    // output col
  const int ar = tm * 16 + l16;    // A row (local)

  // ================= phase 0: F + coef loads =================
  f32x4 v[12];   // v[r] = F[rr + 32*((rt+r)%12)][ch4..ch4+3]; v[0] = own tile row
#pragma unroll
  for (int r = 0; r < 12; ++r) {
    int jr = rt + r; if (jr >= RB_) jr -= RB_;
    v[r] = *(const f32x4*)(Fb + (size_t)(rr + 32 * jr) * C_ + ch4);
  }
  const f32x4 g_lo = *(const f32x4*)&gamma[ch4];
  const f32x4 b_lo = *(const f32x4*)&beta[ch4];
  const f32x4 g_up = *(const f32x4*)&gamma[128 + ch4];
  const f32x4 b_up = *(const f32x4*)&beta[128 + ch4];
  const float bb = bvec[bc];

  // cls-token passthrough
  if (rt == 0 && t < C_)
    out[(size_t)b * LC_ + t] = x[(size_t)b * LC_ + t];

  // ================= stats: sum / sumsq over 12 owned rows =================
  f32x4 s1 = v[0], s2 = v[0] * v[0];
#pragma unroll
  for (int r = 1; r < 12; ++r) { s1 += v[r]; s2 += v[r] * v[r]; }
  // butterfly over rr (masks 2..32 preserve bit0 = half): all lanes get totals
#pragma unroll
  for (int m = 2; m <= 32; m <<= 1) {
#pragma unroll
    for (int j = 0; j < 4; ++j) {
      s1[j] += __shfl_xor(s1[j], m);
      s2[j] += __shfl_xor(s2[j], m);
    }
  }

  // ---- finalize s (every lane, its own 4 channels) ----
  const f32x4 mean = s1 * (1.0f / N_);
  const f32x4 varr = s2 * (1.0f / N_) - mean * mean;
  f32x4 s, sl, sh;
#pragma unroll
  for (int j = 0; j < 4; ++j) {
    const float vv = fmaxf(varr[j], 0.0f);
    s[j]  = g_lo[j] * rsqrtf(vv + EPS_);
    sl[j] = s[j] * LOG2E_;
    sh[j] = sl[j] * mean[j];
  }

  // ================= exp pass (pure regs) =================
  f32x4 se = {0.f, 0.f, 0.f, 0.f}, sf = {0.f, 0.f, 0.f, 0.f};
#pragma unroll
  for (int r = 0; r < 12; ++r) {
#pragma unroll
    for (int j = 0; j < 4; ++j) {
      const float e = fast_exp2(fmaf(sl[j], v[r][j], -sh[j]));
      se[j] += e;
      sf[j] = fmaf(e, v[r][j], sf[j]);
    }
  }

  // ---- issue B-operand W loads now: v[1..11] are dead, 64 f32 transient
  //      fits; latency hides under butterfly2 + As build + barrier ----
  f32x4 wfa[8], wfb[8];
  {
    const float* wrow = W + bc * 256 + lg * 8;
#pragma unroll
    for (int kt = 0; kt < 8; ++kt) {
      wfa[kt] = *(const f32x4*)(wrow + kt * 32);
      wfb[kt] = *(const f32x4*)(wrow + kt * 32 + 4);
    }
  }

#pragma unroll
  for (int m = 2; m <= 32; m <<= 1) {
#pragma unroll
    for (int j = 0; j < 4; ++j) {
      se[j] += __shfl_xor(se[j], m);
      sf[j] += __shfl_xor(sf[j], m);
    }
  }

  // ================= As build from v[0] (already in regs) =================
  {
    const int swzA = (rr & 7) << 3;
    V8u lo, up;
#pragma unroll
    for (int j = 0; j < 4; ++j) {
      const float fac = fmaf(s[j], sf[j] / se[j], b_lo[j]);  // s*M + beta
      lo.us[j] = f2bf(fmaf(-s[j], v[0][j], fac));            // -s*F + fac
      up.us[j] = f2bf(fmaf(g_up[j], v[0][j], b_up[j]));      // g*F + beta
    }
    *(uint2*)&As[rr * 256 + (ch4 ^ swzA)] = lo.u2;
    *(uint2*)&As[rr * 256 + ((128 + ch4) ^ swzA)] = up.u2;
  }

  // ---- convert W fragments to bf16 in regs (no LDS) ----
  short8 bfrag[8];
#pragma unroll
  for (int kt = 0; kt < 8; ++kt) {
    V16 pk;
#pragma unroll
    for (int j = 0; j < 4; ++j) {
      pk.us[j]     = f2bf(wfa[kt][j]);
      pk.us[4 + j] = f2bf(wfb[kt][j]);
    }
    bfrag[kt] = pk.s8;
  }

  __syncthreads();   // the ONLY barrier

  // ================= MFMA: 16 waves x one 16x16 tile, K=256 =================
  {
    const int abase = ar * 256, aswz = (ar & 7) << 3;
    f32x4 acc = {0.f, 0.f, 0.f, 0.f};
#pragma unroll
    for (int kt = 0; kt < 8; ++kt) {
      const int kk = kt * 32 + lg * 8;
      const short8 av = *(const short8*)&As[abase + (kk ^ aswz)];
      acc = __builtin_amdgcn_mfma_f32_16x16x32_bf16(av, bfrag[kt], acc, 0, 0, 0);
    }
    float* ob = out + (size_t)b * LC_;
#pragma unroll
    for (int r = 0; r < 4; ++r) {
      const int m = tm * 16 + lg * 4 + r;
      ob[(size_t)(1 + r0 + m) * C_ + bc] = acc[r] + bb;
    }
  }
}

extern "C" void kernel_launch(void* const* d_in, const int* in_sizes, int n_in,
                              void* d_out, int out_size, void* d_ws, size_t ws_size,
                              hipStream_t stream) {
  const float* x     = (const float*)d_in[0];
  const float* gamma = (const float*)d_in[1];
  const float* beta  = (const float*)d_in[2];
  const float* W     = (const float*)d_in[3];
  const float* bvec  = (const float*)d_in[4];
  float* out = (float*)d_out;

  lnp_kernel<<<B_ * RB_, NTHR_, 0, stream>>>(x, gamma, beta, W, bvec, out);
}

// Round 11
// 15.035 us; speedup vs baseline: 1.1881x; 1.1881x over previous
//
#include <hip/hip_runtime.h>
#include <hip/hip_bf16.h>
#include <math.h>

// Shapes fixed by reference: B=2, L=385, C=128, N=384, 2C=256
// Verified identity (rounds 0-10 all passed):
//   out[b,1+i,c] = b[c] + sum_{kk=0}^{255} (A2[b,i,kk] + fac[b,kk]) * W[c,kk]
//     A2[i,kk]  = -s_kk * F[i,kk]          (kk < 128)
//     A2[i,kk]  =  gamma[kk] * F[i,kk-128] (kk >= 128)
//     fac[kk]   = (kk<128) ? s_kk*M_kk + beta[kk] : beta[kk]
//     s_k       = gamma[k] / sqrt(var_j F[:,k] + eps)
//     M_k       = sum_j softmax_j(s_k F[j,k]) F[j,k]
// This is the round-4 proposal verbatim (best measured: 15.02 us). Later
// structural variants (all-loads-hoisted R7, wave-private single-barrier R9)
// measured identical within noise; prep-split (R6) and global-B-fragments
// (R10) regressed. Overhead/latency-bound regime: replay floor ~13.5 us +
// ~1.5 us irreducible chain.

#define B_  2
#define L_  385
#define C_  128
#define N_  384
#define EPS_ 1e-5f
#define MROWS_ 32
#define RB_  (N_ / MROWS_)   // 12 row-tiles per batch
#define NTHR_ 1024
#define LOG2E_ 1.44269504088896340736f

typedef short short8 __attribute__((ext_vector_type(8)));
typedef float f32x4 __attribute__((ext_vector_type(4)));

union V16 { ushort us[8]; uint4 v4; };

__device__ inline ushort f2bf(float f) {
  __hip_bfloat16 hb = __float2bfloat16(f);   // hw RNE (v_cvt_pk_bf16_f32)
  return __builtin_bit_cast(ushort, hb);
}

__device__ inline float fast_exp2(float xv) {
#if __has_builtin(__builtin_amdgcn_exp2f)
  return __builtin_amdgcn_exp2f(xv);
#else
  float r;
  asm("v_exp_f32 %0, %1" : "=v"(r) : "v"(xv));
  return r;
#endif
}

__global__ __launch_bounds__(NTHR_, 1) void lnp_kernel(
    const float* __restrict__ x, const float* __restrict__ gamma,
    const float* __restrict__ beta, const float* __restrict__ W,
    const float* __restrict__ bvec, float* __restrict__ out) {
  __shared__ __align__(16) float p1[32][128];
  __shared__ __align__(16) float p2[32][128];
  __shared__ __align__(16) float sA[128], slA[128], shA[128];
  __shared__ __align__(16) float facL[256];
  __shared__ __align__(16) ushort Wb[128 * 256];    // [c][kk^((c&7)<<3)] bf16
  __shared__ __align__(16) ushort As[MROWS_ * 256]; // [i][kk^((i&7)<<3)] bf16

  const int blk = blockIdx.x;
  const int b   = blk / RB_;
  const int rt  = blk % RB_;
  const int r0  = rt * MROWS_;
  const int t   = threadIdx.x;

  const float* Fb = x + (size_t)b * (L_ * C_) + C_;  // F[j][c] = Fb[j*128+c]

  // cls-token passthrough
  if (rt == 0 && t < C_)
    out[(size_t)b * (L_ * C_) + t] = x[(size_t)b * (L_ * C_) + t];

  // ---- P1: vectorized F load (cached in regs) + sum/sumsq partials;
  //      Wb bf16 conversion overlapped with the load latency ----
  const int tc = t & 31;        // channel quad index
  const int c4 = tc * 4;        // first of 4 owned channels
  const int h  = t >> 5;        // row group 0..31 (rows h*12 .. h*12+11)
  float4 v[12];
  {
    const float* p = Fb + (size_t)(h * 12) * C_ + c4;
#pragma unroll
    for (int r = 0; r < 12; ++r)
      v[r] = *(const float4*)(p + (size_t)r * C_);

    float ax = 0.f, ay = 0.f, az = 0.f, aw = 0.f;
    float qx = 0.f, qy = 0.f, qz = 0.f, qw = 0.f;
#pragma unroll
    for (int r = 0; r < 12; ++r) {
      ax += v[r].x; qx = fmaf(v[r].x, v[r].x, qx);
      ay += v[r].y; qy = fmaf(v[r].y, v[r].y, qy);
      az += v[r].z; qz = fmaf(v[r].z, v[r].z, qz);
      aw += v[r].w; qw = fmaf(v[r].w, v[r].w, qw);
    }
    float4 s1 = {ax, ay, az, aw};
    float4 s2 = {qx, qy, qz, qw};
    *(float4*)&p1[h][c4] = s1;
    *(float4*)&p2[h][c4] = s2;
  }
  {
    // Wb: thread owns row c = t>>3, 32-kk segment kb = (t&7)*32
    const int c  = t >> 3;
    const int kb = (t & 7) * 32;
    const int swz = (c & 7) << 3;
#pragma unroll
    for (int q = 0; q < 4; ++q) {
      const int kk = kb + q * 8;
      const float* wp = &W[c * 256 + kk];
      const float4 wa  = *(const float4*)wp;
      const float4 wb2 = *(const float4*)(wp + 4);
      V16 pk;
      pk.us[0] = f2bf(wa.x);  pk.us[1] = f2bf(wa.y);
      pk.us[2] = f2bf(wa.z);  pk.us[3] = f2bf(wa.w);
      pk.us[4] = f2bf(wb2.x); pk.us[5] = f2bf(wb2.y);
      pk.us[6] = f2bf(wb2.z); pk.us[7] = f2bf(wb2.w);
      *(uint4*)&Wb[c * 256 + (kk ^ swz)] = pk.v4;
    }
  }
  __syncthreads();  // B1

  // ---- stats finalize (t<128): s, log2-scale, shift ----
  if (t < 128) {
    float s1 = 0.f, s2 = 0.f;
#pragma unroll
    for (int g = 0; g < 32; ++g) { s1 += p1[g][t]; s2 += p2[g][t]; }
    const float mean = s1 * (1.0f / N_);
    const float var  = fmaxf(s2 * (1.0f / N_) - mean * mean, 0.0f);
    const float s    = gamma[t] * rsqrtf(var + EPS_);
    const float sl   = s * LOG2E_;
    sA[t] = s; slA[t] = sl; shA[t] = sl * mean;
    facL[128 + t] = beta[128 + t];     // stats-independent half of fac
  }
  __syncthreads();  // B2

  // ---- P3: softmax moments from cached regs (pure VALU) ----
  {
    const float4 sl4 = *(const float4*)&slA[c4];
    const float4 sh4 = *(const float4*)&shA[c4];
    float ex = 0.f, ey = 0.f, ez = 0.f, ew = 0.f;
    float fx = 0.f, fy = 0.f, fz = 0.f, fw = 0.f;
#pragma unroll
    for (int r = 0; r < 12; ++r) {
      const float e0 = fast_exp2(fmaf(sl4.x, v[r].x, -sh4.x));
      const float e1 = fast_exp2(fmaf(sl4.y, v[r].y, -sh4.y));
      const float e2 = fast_exp2(fmaf(sl4.z, v[r].z, -sh4.z));
      const float e3 = fast_exp2(fmaf(sl4.w, v[r].w, -sh4.w));
      ex += e0; fx = fmaf(e0, v[r].x, fx);
      ey += e1; fy = fmaf(e1, v[r].y, fy);
      ez += e2; fz = fmaf(e2, v[r].z, fz);
      ew += e3; fw = fmaf(e3, v[r].w, fw);
    }
    float4 se = {ex, ey, ez, ew};
    float4 sf = {fx, fy, fz, fw};
    *(float4*)&p1[h][c4] = se;
    *(float4*)&p2[h][c4] = sf;
  }

  // ---- issue As row loads early (independent of fac) ----
  const int ai  = t >> 5;            // local row 0..31
  const int kk0 = (t & 31) * 8;      // kk chunk start
  const int ks  = kk0 & 127;         // source channel
  float4 af0, af1, g40 = {0,0,0,0}, g41 = {0,0,0,0};
  {
    const float* fp = Fb + (size_t)(r0 + ai) * C_ + ks;
    af0 = *(const float4*)fp;
    af1 = *(const float4*)(fp + 4);
    if (kk0 >= 128) {
      g40 = *(const float4*)&gamma[kk0];
      g41 = *(const float4*)&gamma[kk0 + 4];
    }
  }
  __syncthreads();  // B3

  // ---- upper-half As (beta branch, fac already known) ||
  //      fac finalize (t<128) ----
  const int aswz_w = (ai & 7) << 3;
  if (kk0 >= 128) {
    const float4 fc0 = *(const float4*)&facL[kk0];
    const float4 fc1 = *(const float4*)&facL[kk0 + 4];
    V16 pk;
    pk.us[0] = f2bf(fmaf(g40.x, af0.x, fc0.x));
    pk.us[1] = f2bf(fmaf(g40.y, af0.y, fc0.y));
    pk.us[2] = f2bf(fmaf(g40.z, af0.z, fc0.z));
    pk.us[3] = f2bf(fmaf(g40.w, af0.w, fc0.w));
    pk.us[4] = f2bf(fmaf(g41.x, af1.x, fc1.x));
    pk.us[5] = f2bf(fmaf(g41.y, af1.y, fc1.y));
    pk.us[6] = f2bf(fmaf(g41.z, af1.z, fc1.z));
    pk.us[7] = f2bf(fmaf(g41.w, af1.w, fc1.w));
    *(uint4*)&As[ai * 256 + (kk0 ^ aswz_w)] = pk.v4;
  }
  if (t < 128) {
    float se = 0.f, sf = 0.f;
#pragma unroll
    for (int g = 0; g < 32; ++g) { se += p1[g][t]; sf += p2[g][t]; }
    facL[t] = fmaf(sA[t], sf / se, beta[t]);
  }
  __syncthreads();  // B4

  // ---- lower-half As (needs fac) ----
  if (kk0 < 128) {
    const float4 sa0 = *(const float4*)&sA[kk0];
    const float4 sa1 = *(const float4*)&sA[kk0 + 4];
    const float4 fc0 = *(const float4*)&facL[kk0];
    const float4 fc1 = *(const float4*)&facL[kk0 + 4];
    V16 pk;
    pk.us[0] = f2bf(fmaf(-sa0.x, af0.x, fc0.x));
    pk.us[1] = f2bf(fmaf(-sa0.y, af0.y, fc0.y));
    pk.us[2] = f2bf(fmaf(-sa0.z, af0.z, fc0.z));
    pk.us[3] = f2bf(fmaf(-sa0.w, af0.w, fc0.w));
    pk.us[4] = f2bf(fmaf(-sa1.x, af1.x, fc1.x));
    pk.us[5] = f2bf(fmaf(-sa1.y, af1.y, fc1.y));
    pk.us[6] = f2bf(fmaf(-sa1.z, af1.z, fc1.z));
    pk.us[7] = f2bf(fmaf(-sa1.w, af1.w, fc1.w));
    *(uint4*)&As[ai * 256 + (kk0 ^ aswz_w)] = pk.v4;
  }
  __syncthreads();  // B5

  // ---- MFMA: 16 waves x one 16x16 tile, K=256 (verified layout) ----
  {
    const int w   = t >> 6;
    const int l   = t & 63;
    const int tn  = w & 7;
    const int tm  = w >> 3;
    const int l16 = l & 15;
    const int lg  = l >> 4;

    const int ar = tm * 16 + l16;
    const int bc = tn * 16 + l16;
    const int abase = ar * 256;
    const int bbase = bc * 256;
    const int aswz = (ar & 7) << 3;
    const int bswz = (bc & 7) << 3;

    f32x4 acc = {0.f, 0.f, 0.f, 0.f};
#pragma unroll
    for (int kt = 0; kt < 8; ++kt) {
      const int kk = kt * 32 + lg * 8;
      const short8 av = *(const short8*)&As[abase + (kk ^ aswz)];
      const short8 bv = *(const short8*)&Wb[bbase + (kk ^ bswz)];
      acc = __builtin_amdgcn_mfma_f32_16x16x32_bf16(av, bv, acc, 0, 0, 0);
    }

    const float bb = bvec[bc];
    float* ob = out + (size_t)b * (L_ * C_);
#pragma unroll
    for (int r = 0; r < 4; ++r) {
      const int m = tm * 16 + lg * 4 + r;
      ob[(size_t)(1 + r0 + m) * C_ + bc] = acc[r] + bb;
    }
  }
}

extern "C" void kernel_launch(void* const* d_in, const int* in_sizes, int n_in,
                              void* d_out, int out_size, void* d_ws, size_t ws_size,
                              hipStream_t stream) {
  const float* x     = (const float*)d_in[0];
  const float* gamma = (const float*)d_in[1];
  const float* beta  = (const float*)d_in[2];
  const float* W     = (const float*)d_in[3];
  const float* bvec  = (const float*)d_in[4];
  float* out = (float*)d_out;

  lnp_kernel<<<B_ * RB_, NTHR_, 0, stream>>>(x, gamma, beta, W, bvec, out);
}